// Round 1
// baseline (251.448 us; speedup 1.0000x reference)
//
#include <hip/hip_runtime.h>
#include <math.h>

#define E_DIM 2048

__device__ __forceinline__ float siluf(float v) { return v / (1.f + expf(-v)); }

// ---------------- LayerNorm over last dim (1024) ----------------
__global__ __launch_bounds__(256) void ln_kernel(const float* __restrict__ x,
                                                 const float* __restrict__ g,
                                                 const float* __restrict__ be,
                                                 float* __restrict__ h) {
    int b = blockIdx.x;
    int tid = threadIdx.x;
    __shared__ float sdata[256];
    const float* xr = x + b * 1024;
    float v[4];
    float s = 0.f;
#pragma unroll
    for (int i = 0; i < 4; ++i) { v[i] = xr[tid + i * 256]; s += v[i]; }
    sdata[tid] = s; __syncthreads();
    for (int st = 128; st > 0; st >>= 1) { if (tid < st) sdata[tid] += sdata[tid + st]; __syncthreads(); }
    float mu = sdata[0] * (1.f / 1024.f);
    __syncthreads();
    float s2 = 0.f;
#pragma unroll
    for (int i = 0; i < 4; ++i) { float d = v[i] - mu; s2 += d * d; }
    sdata[tid] = s2; __syncthreads();
    for (int st = 128; st > 0; st >>= 1) { if (tid < st) sdata[tid] += sdata[tid + st]; __syncthreads(); }
    float var = sdata[0] * (1.f / 1024.f);
    float inv = rsqrtf(var + 1e-5f);
    float* hr = h + b * 1024;
#pragma unroll
    for (int i = 0; i < 4; ++i) {
        int j = tid + i * 256;
        hr[j] = (v[i] - mu) * inv * g[j] + be[j];
    }
}

// ---------------- Generic split-K GEMM: C += A(128 x K, lda) * B(K x N, ldb) ----------------
// BM=64, BN=64, BK=16, 256 threads, 4x4 microtile, atomicAdd epilogue.
__global__ __launch_bounds__(256) void gemm_splitk(const float* __restrict__ A, int lda,
                                                   const float* __restrict__ B, int ldb,
                                                   float* __restrict__ C, int ldc,
                                                   int K, int kChunk) {
    __shared__ float As[16][68];  // [k][m], padded (+4) -> 2-way max on store
    __shared__ float Bs[16][64];  // [k][n]
    const int n0 = blockIdx.x * 64;
    const int m0 = blockIdx.y * 64;
    int k0 = blockIdx.z * kChunk;
    const int kend = min(K, k0 + kChunk);
    const int tid = threadIdx.x;
    const int ty = tid >> 4, tx = tid & 15;
    float acc[4][4] = {};
    for (; k0 < kend; k0 += 16) {
#pragma unroll
        for (int i = 0; i < 4; ++i) {  // A tile: 64 rows x 16 cols
            int idx = tid + i * 256;
            int r = idx >> 4, cc = idx & 15;
            As[cc][r] = A[(m0 + r) * lda + (k0 + cc)];
        }
#pragma unroll
        for (int i = 0; i < 4; ++i) {  // B tile: 16 rows x 64 cols
            int idx = tid + i * 256;
            int r = idx >> 6, cc = idx & 63;
            Bs[r][cc] = B[(k0 + r) * ldb + (n0 + cc)];
        }
        __syncthreads();
#pragma unroll
        for (int kk = 0; kk < 16; ++kk) {
            float av[4], bv[4];
            *(float4*)av = *(const float4*)&As[kk][ty * 4];
            *(float4*)bv = *(const float4*)&Bs[kk][tx * 4];
#pragma unroll
            for (int i = 0; i < 4; ++i)
#pragma unroll
                for (int j = 0; j < 4; ++j)
                    acc[i][j] = fmaf(av[i], bv[j], acc[i][j]);
        }
        __syncthreads();
    }
#pragma unroll
    for (int i = 0; i < 4; ++i)
#pragma unroll
        for (int j = 0; j < 4; ++j)
            atomicAdd(&C[(m0 + ty * 4 + i) * ldc + (n0 + tx * 4 + j)], acc[i][j]);
}

// ---------------- Epilogues ----------------
// e1: xz (128x4096) -> u = silu(xi*cw3+cb) (128x2048), sres = silu(res) (128x2048)
__global__ __launch_bounds__(256) void e1_kernel(const float* __restrict__ xz,
                                                 const float* __restrict__ convw,
                                                 const float* __restrict__ convb,
                                                 float* __restrict__ u,
                                                 float* __restrict__ sres) {
    int idx = blockIdx.x * 256 + threadIdx.x;  // 128*4096
    int b = idx >> 12, j = idx & 4095;
    float val = xz[idx];
    if (j < E_DIM) {
        float xc = val * convw[3 * E_DIM + j] + convb[j];
        u[b * E_DIM + j] = siluf(xc);
    } else {
        sres[b * E_DIM + (j - E_DIM)] = siluf(val);
    }
}

// svec[b] = dot(Bm[b], Cm[b]) from x_dbl (128x1536, cols 512:1024 and 1024:1536)
__global__ __launch_bounds__(256) void svec_kernel(const float* __restrict__ xdbl,
                                                   float* __restrict__ svec) {
    int b = blockIdx.x;
    int tid = threadIdx.x;
    __shared__ float sdata[256];
    const float* row = xdbl + b * 1536;
    float s = 0.f;
    for (int n = tid; n < 512; n += 256) s += row[512 + n] * row[1024 + n];
    sdata[tid] = s; __syncthreads();
    for (int st = 128; st > 0; st >>= 1) { if (tid < st) sdata[tid] += sdata[tid + st]; __syncthreads(); }
    if (tid == 0) svec[b] = sdata[0];
}

// e3: y = u * (softplus(dacc + b_dt) * svec[b] + D) * sres   (128x2048)
__global__ __launch_bounds__(256) void e3_kernel(const float* __restrict__ dacc,
                                                 const float* __restrict__ b_dt,
                                                 const float* __restrict__ u,
                                                 const float* __restrict__ sres,
                                                 const float* __restrict__ svec,
                                                 const float* __restrict__ Dv,
                                                 float* __restrict__ y) {
    int idx = blockIdx.x * 256 + threadIdx.x;  // 128*2048
    int b = idx >> 11, j = idx & 2047;
    float t = dacc[idx] + b_dt[j];
    float delta = fmaxf(t, 0.f) + log1pf(expf(-fabsf(t)));  // stable softplus
    y[idx] = u[idx] * (delta * svec[b] + Dv[j]) * sres[idx];
}

// e4: mamba = mo_acc + b_out + x   (128x1024)
__global__ __launch_bounds__(256) void e4_kernel(const float* __restrict__ mo,
                                                 const float* __restrict__ b_out,
                                                 const float* __restrict__ x,
                                                 float* __restrict__ mamba) {
    int idx = blockIdx.x * 256 + threadIdx.x;  // 128*1024
    int j = idx & 1023;
    mamba[idx] = mo[idx] + b_out[j] + x[idx];
}

// e5: z = gelu(zd + b_d) * (gb[:, :512]+b_f[:512]) + (gb[:, 512:]+b_f[512:])   (128x512)
__global__ __launch_bounds__(256) void e5_kernel(const float* __restrict__ zd,
                                                 const float* __restrict__ b_d,
                                                 const float* __restrict__ gb,
                                                 const float* __restrict__ b_f,
                                                 float* __restrict__ z) {
    int idx = blockIdx.x * 256 + threadIdx.x;  // 128*512
    int b = idx >> 9, n = idx & 511;
    float t = zd[idx] + b_d[n];
    float zg = 0.5f * t * (1.f + erff(t * 0.70710678118654752f));
    float g = gb[b * 1024 + n] + b_f[n];
    float bb = gb[b * 1024 + 512 + n] + b_f[512 + n];
    z[idx] = zg * g + bb;
}

// e6: out = out_acc + b_o   (128x1024)
__global__ __launch_bounds__(256) void e6_kernel(const float* __restrict__ oa,
                                                 const float* __restrict__ b_o,
                                                 float* __restrict__ out) {
    int idx = blockIdx.x * 256 + threadIdx.x;  // 128*1024
    int j = idx & 1023;
    out[idx] = oa[idx] + b_o[j];
}

extern "C" void kernel_launch(void* const* d_in, const int* in_sizes, int n_in,
                              void* d_out, int out_size, void* d_ws, size_t ws_size,
                              hipStream_t stream) {
    (void)in_sizes; (void)n_in; (void)out_size; (void)ws_size;
    const float* x     = (const float*)d_in[0];
    const float* c     = (const float*)d_in[1];
    const float* ln_g  = (const float*)d_in[2];
    const float* ln_b  = (const float*)d_in[3];
    const float* W_in  = (const float*)d_in[4];
    const float* convw = (const float*)d_in[5];
    const float* convb = (const float*)d_in[6];
    const float* W_x   = (const float*)d_in[7];
    const float* W_dt  = (const float*)d_in[8];
    const float* b_dt  = (const float*)d_in[9];
    // d_in[10] = A_log: provably unused (scan length 1 from h0 = 0)
    const float* Dv    = (const float*)d_in[11];
    const float* W_out = (const float*)d_in[12];
    const float* b_out = (const float*)d_in[13];
    const float* W_d   = (const float*)d_in[14];
    const float* b_d   = (const float*)d_in[15];
    const float* W_f   = (const float*)d_in[16];
    const float* b_f   = (const float*)d_in[17];
    const float* W_o   = (const float*)d_in[18];
    const float* b_o   = (const float*)d_in[19];
    float* out = (float*)d_out;

    char* ws = (char*)d_ws;
    size_t off = 0;
    auto alloc = [&](size_t nElem) { float* p = (float*)(ws + off); off += nElem * sizeof(float); return p; };
    // accumulator region (memset to zero each launch)
    float* xz_acc   = alloc(128 * 4096);
    float* xdbl_acc = alloc(128 * 1536);
    float* dacc     = alloc(128 * 2048);
    float* mo_acc   = alloc(128 * 1024);
    float* zd_acc   = alloc(128 * 512);
    float* gb_acc   = alloc(128 * 1024);
    float* out_acc  = alloc(128 * 1024);
    size_t accBytes = off;
    // plain scratch
    float* h     = alloc(128 * 1024);
    float* u     = alloc(128 * 2048);
    float* sres  = alloc(128 * 2048);
    float* svec  = alloc(128);
    float* y     = alloc(128 * 2048);
    float* mamba = alloc(128 * 1024);
    float* z     = alloc(128 * 512);

    hipMemsetAsync(d_ws, 0, accBytes, stream);

    // LayerNorm
    ln_kernel<<<128, 256, 0, stream>>>(x, ln_g, ln_b, h);
    // G1: h(128x1024) @ W_in(1024x4096) -> xz_acc   [S=2, chunk 512]
    gemm_splitk<<<dim3(64, 2, 2), 256, 0, stream>>>(h, 1024, W_in, 4096, xz_acc, 4096, 1024, 512);
    e1_kernel<<<(128 * 4096) / 256, 256, 0, stream>>>(xz_acc, convw, convb, u, sres);
    // G6 (independent): c(128x512) @ W_f(512x1024) -> gb_acc   [S=8, chunk 64]
    gemm_splitk<<<dim3(16, 2, 8), 256, 0, stream>>>(c, 512, W_f, 1024, gb_acc, 1024, 512, 64);
    // G2: u(128x2048) @ W_x(2048x1536) -> xdbl_acc   [S=6, chunk 352]
    gemm_splitk<<<dim3(24, 2, 6), 256, 0, stream>>>(u, 2048, W_x, 1536, xdbl_acc, 1536, 2048, 352);
    svec_kernel<<<128, 256, 0, stream>>>(xdbl_acc, svec);
    // G3: d_r = xdbl[:, :512] (lda=1536) @ W_dt(512x2048) -> dacc   [S=4, chunk 128]
    gemm_splitk<<<dim3(32, 2, 4), 256, 0, stream>>>(xdbl_acc, 1536, W_dt, 2048, dacc, 2048, 512, 128);
    e3_kernel<<<(128 * 2048) / 256, 256, 0, stream>>>(dacc, b_dt, u, sres, svec, Dv, y);
    // G4: y(128x2048) @ W_out(2048x1024) -> mo_acc   [S=8, chunk 256]
    gemm_splitk<<<dim3(16, 2, 8), 256, 0, stream>>>(y, 2048, W_out, 1024, mo_acc, 1024, 2048, 256);
    e4_kernel<<<(128 * 1024) / 256, 256, 0, stream>>>(mo_acc, b_out, x, mamba);
    // G5: mamba(128x1024) @ W_d(1024x512) -> zd_acc   [S=16, chunk 64]
    gemm_splitk<<<dim3(8, 2, 16), 256, 0, stream>>>(mamba, 1024, W_d, 512, zd_acc, 512, 1024, 64);
    e5_kernel<<<(128 * 512) / 256, 256, 0, stream>>>(zd_acc, b_d, gb_acc, b_f, z);
    // G7: z(128x512) @ W_o(512x1024) -> out_acc   [S=8, chunk 64]
    gemm_splitk<<<dim3(16, 2, 8), 256, 0, stream>>>(z, 512, W_o, 1024, out_acc, 1024, 512, 64);
    e6_kernel<<<(128 * 1024) / 256, 256, 0, stream>>>(out_acc, b_o, out);
}

// Round 2
// 91.393 us; speedup vs baseline: 2.7513x; 2.7513x over previous
//
#include <hip/hip_runtime.h>
#include <math.h>

#define E_DIM 2048

typedef __attribute__((ext_vector_type(8))) short short8;
typedef __attribute__((ext_vector_type(4))) float floatx4;

__device__ __forceinline__ float siluf(float v) { return v / (1.f + expf(-v)); }

// f32 -> bf16 bits, round-to-nearest-even
__device__ __forceinline__ short f2bf(float f) {
    unsigned u = __float_as_uint(f);
    u += 0x7fffu + ((u >> 16) & 1u);
    return (short)(u >> 16);
}

// ---------------- LayerNorm (1024) -> bf16 h ; also convert c -> bf16 ----------------
__global__ __launch_bounds__(256) void ln_cvt_kernel(const float* __restrict__ x,
                                                     const float* __restrict__ g,
                                                     const float* __restrict__ be,
                                                     const float* __restrict__ c,
                                                     short* __restrict__ h_bf,
                                                     short* __restrict__ c_bf) {
    int b = blockIdx.x;
    int tid = threadIdx.x;
    __shared__ float sdata[256];
    const float* xr = x + b * 1024;
    float v[4];
    float s = 0.f;
#pragma unroll
    for (int i = 0; i < 4; ++i) { v[i] = xr[tid + i * 256]; s += v[i]; }
    sdata[tid] = s; __syncthreads();
    for (int st = 128; st > 0; st >>= 1) { if (tid < st) sdata[tid] += sdata[tid + st]; __syncthreads(); }
    float mu = sdata[0] * (1.f / 1024.f);
    __syncthreads();
    float s2 = 0.f;
#pragma unroll
    for (int i = 0; i < 4; ++i) { float d = v[i] - mu; s2 += d * d; }
    sdata[tid] = s2; __syncthreads();
    for (int st = 128; st > 0; st >>= 1) { if (tid < st) sdata[tid] += sdata[tid + st]; __syncthreads(); }
    float var = sdata[0] * (1.f / 1024.f);
    float inv = rsqrtf(var + 1e-5f);
    short* hr = h_bf + b * 1024;
#pragma unroll
    for (int i = 0; i < 4; ++i) {
        int j = tid + i * 256;
        hr[j] = f2bf((v[i] - mu) * inv * g[j] + be[j]);
    }
    // convert conditioning row to bf16 (feeds G6)
    const float* cr = c + b * 512;
    short* cbr = c_bf + b * 512;
    for (int j = tid; j < 512; j += 256) cbr[j] = f2bf(cr[j]);
}

// ---------------- MFMA split-K GEMM: C += A_bf16(128 x K) * bf16(B_f32(K x N)) ----------------
// Block = 4 waves; wave w owns rows [w*32, w*32+32), block owns cols [bx*64, bx*64+64).
// No LDS, no barriers: B re-reads across the 4 waves hit L1/L2.
__global__ __launch_bounds__(256) void gemm_mfma(const short* __restrict__ A, int lda,
                                                 const float* __restrict__ B, int ldb,
                                                 float* __restrict__ C, int ldc,
                                                 int kChunk) {
    const int tid = threadIdx.x;
    const int w = tid >> 6;
    const int l = tid & 63;
    const int lane15 = l & 15;
    const int lgrp = l >> 4;
    const int n0 = blockIdx.x * 64;
    const int k0 = blockIdx.z * kChunk;

    const short* Ap0 = A + (w * 32 + lane15) * lda + lgrp * 8 + k0;
    const short* Ap1 = Ap0 + 16 * lda;
    const float* Bp = B + (size_t)(k0 + lgrp * 8) * ldb + n0 + lane15;

    floatx4 acc[2][4];
#pragma unroll
    for (int i = 0; i < 2; ++i)
#pragma unroll
        for (int j = 0; j < 4; ++j) acc[i][j] = (floatx4)0.f;

    for (int ks = 0; ks < kChunk; ks += 32) {
        short8 a0 = *(const short8*)(Ap0);
        short8 a1 = *(const short8*)(Ap1);
        Ap0 += 32; Ap1 += 32;
        float bv[4][8];
#pragma unroll
        for (int i = 0; i < 8; ++i) {
            const float* Br = Bp + i * ldb;
#pragma unroll
            for (int nt = 0; nt < 4; ++nt) bv[nt][i] = Br[nt * 16];
        }
        Bp += 32 * (size_t)ldb;
        short8 vb[4];
#pragma unroll
        for (int nt = 0; nt < 4; ++nt)
#pragma unroll
            for (int i = 0; i < 8; ++i) vb[nt][i] = f2bf(bv[nt][i]);
#pragma unroll
        for (int nt = 0; nt < 4; ++nt) {
            acc[0][nt] = __builtin_amdgcn_mfma_f32_16x16x32_bf16(a0, vb[nt], acc[0][nt], 0, 0, 0);
            acc[1][nt] = __builtin_amdgcn_mfma_f32_16x16x32_bf16(a1, vb[nt], acc[1][nt], 0, 0, 0);
        }
    }
    const int rbase = w * 32 + lgrp * 4;
#pragma unroll
    for (int mf = 0; mf < 2; ++mf)
#pragma unroll
        for (int nt = 0; nt < 4; ++nt)
#pragma unroll
            for (int r = 0; r < 4; ++r)
                atomicAdd(&C[(rbase + mf * 16 + r) * ldc + n0 + nt * 16 + lane15], acc[mf][nt][r]);
}

// ---------------- Epilogues ----------------
// e1: xz (128x4096) -> u = silu(xi*cw3+cb) (f32 + bf16), sres = silu(res) (f32)
__global__ __launch_bounds__(256) void e1_kernel(const float* __restrict__ xz,
                                                 const float* __restrict__ convw,
                                                 const float* __restrict__ convb,
                                                 float* __restrict__ u_f32,
                                                 short* __restrict__ u_bf,
                                                 float* __restrict__ sres) {
    int idx = blockIdx.x * 256 + threadIdx.x;  // 128*4096
    int b = idx >> 12, j = idx & 4095;
    float val = xz[idx];
    if (j < E_DIM) {
        float xc = val * convw[3 * E_DIM + j] + convb[j];
        float s = siluf(xc);
        u_f32[b * E_DIM + j] = s;
        u_bf[b * E_DIM + j] = f2bf(s);
    } else {
        sres[b * E_DIM + (j - E_DIM)] = siluf(val);
    }
}

// svec[b] = dot(Bm[b], Cm[b]); also convert d_r row (cols 0:512 of xdbl) to bf16
__global__ __launch_bounds__(256) void svec_cvt_kernel(const float* __restrict__ xdbl,
                                                       float* __restrict__ svec,
                                                       short* __restrict__ dr_bf) {
    int b = blockIdx.x;
    int tid = threadIdx.x;
    __shared__ float sdata[256];
    const float* row = xdbl + b * 1536;
    float s = 0.f;
    for (int n = tid; n < 512; n += 256) s += row[512 + n] * row[1024 + n];
    sdata[tid] = s; __syncthreads();
    for (int st = 128; st > 0; st >>= 1) { if (tid < st) sdata[tid] += sdata[tid + st]; __syncthreads(); }
    if (tid == 0) svec[b] = sdata[0];
    short* dr = dr_bf + b * 512;
    for (int n = tid; n < 512; n += 256) dr[n] = f2bf(row[n]);
}

// e3: y = u * (softplus(dacc + b_dt) * svec[b] + D) * sres  -> bf16
__global__ __launch_bounds__(256) void e3_kernel(const float* __restrict__ dacc,
                                                 const float* __restrict__ b_dt,
                                                 const float* __restrict__ u,
                                                 const float* __restrict__ sres,
                                                 const float* __restrict__ svec,
                                                 const float* __restrict__ Dv,
                                                 short* __restrict__ y_bf) {
    int idx = blockIdx.x * 256 + threadIdx.x;  // 128*2048
    int b = idx >> 11, j = idx & 2047;
    float t = dacc[idx] + b_dt[j];
    float delta = fmaxf(t, 0.f) + log1pf(expf(-fabsf(t)));  // stable softplus
    y_bf[idx] = f2bf(u[idx] * (delta * svec[b] + Dv[j]) * sres[idx]);
}

// e4: mamba = mo_acc + b_out + x  -> bf16
__global__ __launch_bounds__(256) void e4_kernel(const float* __restrict__ mo,
                                                 const float* __restrict__ b_out,
                                                 const float* __restrict__ x,
                                                 short* __restrict__ mamba_bf) {
    int idx = blockIdx.x * 256 + threadIdx.x;  // 128*1024
    int j = idx & 1023;
    mamba_bf[idx] = f2bf(mo[idx] + b_out[j] + x[idx]);
}

// e5: z = gelu(zd + b_d) * (gb[:, :512]+b_f[:512]) + (gb[:, 512:]+b_f[512:]) -> bf16
__global__ __launch_bounds__(256) void e5_kernel(const float* __restrict__ zd,
                                                 const float* __restrict__ b_d,
                                                 const float* __restrict__ gb,
                                                 const float* __restrict__ b_f,
                                                 short* __restrict__ z_bf) {
    int idx = blockIdx.x * 256 + threadIdx.x;  // 128*512
    int b = idx >> 9, n = idx & 511;
    float t = zd[idx] + b_d[n];
    float zg = 0.5f * t * (1.f + erff(t * 0.70710678118654752f));
    float gq = gb[b * 1024 + n] + b_f[n];
    float bb = gb[b * 1024 + 512 + n] + b_f[512 + n];
    z_bf[idx] = f2bf(zg * gq + bb);
}

// e6: out = out_acc + b_o   (f32)
__global__ __launch_bounds__(256) void e6_kernel(const float* __restrict__ oa,
                                                 const float* __restrict__ b_o,
                                                 float* __restrict__ out) {
    int idx = blockIdx.x * 256 + threadIdx.x;  // 128*1024
    int j = idx & 1023;
    out[idx] = oa[idx] + b_o[j];
}

extern "C" void kernel_launch(void* const* d_in, const int* in_sizes, int n_in,
                              void* d_out, int out_size, void* d_ws, size_t ws_size,
                              hipStream_t stream) {
    (void)in_sizes; (void)n_in; (void)out_size; (void)ws_size;
    const float* x     = (const float*)d_in[0];
    const float* c     = (const float*)d_in[1];
    const float* ln_g  = (const float*)d_in[2];
    const float* ln_b  = (const float*)d_in[3];
    const float* W_in  = (const float*)d_in[4];
    const float* convw = (const float*)d_in[5];
    const float* convb = (const float*)d_in[6];
    const float* W_x   = (const float*)d_in[7];
    const float* W_dt  = (const float*)d_in[8];
    const float* b_dt  = (const float*)d_in[9];
    // d_in[10] = A_log: provably unused (scan length 1 from h0 = 0)
    const float* Dv    = (const float*)d_in[11];
    const float* W_out = (const float*)d_in[12];
    const float* b_out = (const float*)d_in[13];
    const float* W_d   = (const float*)d_in[14];
    const float* b_d   = (const float*)d_in[15];
    const float* W_f   = (const float*)d_in[16];
    const float* b_f   = (const float*)d_in[17];
    const float* W_o   = (const float*)d_in[18];
    const float* b_o   = (const float*)d_in[19];
    float* out = (float*)d_out;

    char* ws = (char*)d_ws;
    size_t off = 0;
    auto allocf = [&](size_t nElem) { float* p = (float*)(ws + off); off += nElem * sizeof(float); return p; };
    auto allocs = [&](size_t nElem) { short* p = (short*)(ws + off); off += nElem * sizeof(short); return p; };
    // accumulator region (memset to zero each launch)
    float* xz_acc   = allocf(128 * 4096);
    float* xdbl_acc = allocf(128 * 1536);
    float* dacc     = allocf(128 * 2048);
    float* mo_acc   = allocf(128 * 1024);
    float* zd_acc   = allocf(128 * 512);
    float* gb_acc   = allocf(128 * 1024);
    float* out_acc  = allocf(128 * 1024);
    size_t accBytes = off;
    // plain scratch
    float* u_f32  = allocf(128 * 2048);
    float* sres   = allocf(128 * 2048);
    float* svec   = allocf(128);
    short* h_bf   = allocs(128 * 1024);
    short* c_bf   = allocs(128 * 512);
    short* u_bf   = allocs(128 * 2048);
    short* dr_bf  = allocs(128 * 512);
    short* y_bf   = allocs(128 * 2048);
    short* mamba_bf = allocs(128 * 1024);
    short* z_bf   = allocs(128 * 512);

    hipMemsetAsync(d_ws, 0, accBytes, stream);

    // LayerNorm (+ c -> bf16)
    ln_cvt_kernel<<<128, 256, 0, stream>>>(x, ln_g, ln_b, c, h_bf, c_bf);
    // G1: h(128x1024) @ W_in(1024x4096) -> xz_acc   [S=4, chunk 256]
    gemm_mfma<<<dim3(64, 1, 4), 256, 0, stream>>>(h_bf, 1024, W_in, 4096, xz_acc, 4096, 256);
    // G6 (independent of G1 chain): c(128x512) @ W_f(512x1024) -> gb_acc  [S=8, chunk 64]
    gemm_mfma<<<dim3(16, 1, 8), 256, 0, stream>>>(c_bf, 512, W_f, 1024, gb_acc, 1024, 64);
    e1_kernel<<<(128 * 4096) / 256, 256, 0, stream>>>(xz_acc, convw, convb, u_f32, u_bf, sres);
    // G2: u(128x2048) @ W_x(2048x1536) -> xdbl_acc   [S=8, chunk 256]
    gemm_mfma<<<dim3(24, 1, 8), 256, 0, stream>>>(u_bf, 2048, W_x, 1536, xdbl_acc, 1536, 256);
    svec_cvt_kernel<<<128, 256, 0, stream>>>(xdbl_acc, svec, dr_bf);
    // G3: d_r(128x512) @ W_dt(512x2048) -> dacc   [S=8, chunk 64]
    gemm_mfma<<<dim3(32, 1, 8), 256, 0, stream>>>(dr_bf, 512, W_dt, 2048, dacc, 2048, 64);
    e3_kernel<<<(128 * 2048) / 256, 256, 0, stream>>>(dacc, b_dt, u_f32, sres, svec, Dv, y_bf);
    // G4: y(128x2048) @ W_out(2048x1024) -> mo_acc   [S=8, chunk 256]
    gemm_mfma<<<dim3(16, 1, 8), 256, 0, stream>>>(y_bf, 2048, W_out, 1024, mo_acc, 1024, 256);
    e4_kernel<<<(128 * 1024) / 256, 256, 0, stream>>>(mo_acc, b_out, x, mamba_bf);
    // G5: mamba(128x1024) @ W_d(1024x512) -> zd_acc   [S=16, chunk 64]
    gemm_mfma<<<dim3(8, 1, 16), 256, 0, stream>>>(mamba_bf, 1024, W_d, 512, zd_acc, 512, 64);
    e5_kernel<<<(128 * 512) / 256, 256, 0, stream>>>(zd_acc, b_d, gb_acc, b_f, z_bf);
    // G7: z(128x512) @ W_o(512x1024) -> out_acc   [S=8, chunk 64]
    gemm_mfma<<<dim3(16, 1, 8), 256, 0, stream>>>(z_bf, 512, W_o, 1024, out_acc, 1024, 64);
    e6_kernel<<<(128 * 1024) / 256, 256, 0, stream>>>(out_acc, b_o, out);
}